// Round 2
// baseline (1418.263 us; speedup 1.0000x reference)
//
#include <hip/hip_runtime.h>
#include <cstdint>
#include <cstddef>

#define B 8
#define C 192
#define H 128
#define W 128
#define HW (H * W)
#define CHW ((size_t)C * HW)

// ---------------- LayerNorm over channel dim ----------------
// grid: nb*HW/256 blocks of 256; processes nb batches starting at x (already offset)
__global__ void ln_kernel(const float* __restrict__ x, const float* __restrict__ lw,
                          const float* __restrict__ lb, float* __restrict__ z) {
    int p = blockIdx.x * blockDim.x + threadIdx.x;   // [0, nb*HW)
    int b = p / HW, hw = p % HW;
    const float* xp = x + (size_t)b * CHW + hw;
    float sum = 0.f, sq = 0.f;
    for (int c = 0; c < C; ++c) {
        float v = xp[(size_t)c * HW];
        sum += v; sq += v * v;
    }
    float mean = sum * (1.0f / C);
    float var = fmaxf(sq * (1.0f / C) - mean * mean, 0.f);
    float rs = rsqrtf(var + 1e-6f);
    float* zp = z + (size_t)b * CHW + hw;
    for (int c = 0; c < C; ++c) {
        float v = xp[(size_t)c * HW];
        zp[(size_t)c * HW] = (v - mean) * rs * lw[c] + lb[c];
    }
}

// ---------------- gate conv: 3C outputs, sigmoid, u=beta*z fused ----------------
// grid: (3C/8, nb*H), block 128 (one thread per w)
__global__ void gates_conv_kernel(const float* __restrict__ z, const float* __restrict__ wgt,
                                  const float* __restrict__ bias,
                                  float* __restrict__ A, float* __restrict__ U,
                                  float* __restrict__ G) {
    int w = threadIdx.x;
    int o0 = blockIdx.x * 8;          // output channel block within [0,3C)
    int bh = blockIdx.y;
    int b = bh / H, h = bh % H;
    float acc[8];
#pragma unroll
    for (int j = 0; j < 8; ++j) acc[j] = bias[o0 + j];
    const float* ip = z + (size_t)b * CHW + h * W + w;
#pragma unroll 4
    for (int c = 0; c < C; ++c) {
        float v = ip[(size_t)c * HW];
#pragma unroll
        for (int j = 0; j < 8; ++j)
            acc[j] += wgt[(o0 + j) * C + c] * v;
    }
    int gtype = o0 / C;               // 0=alpha 1=beta 2=gamma (8-blocks never straddle)
    int oc = o0 - gtype * C;
    float* dst = (gtype == 0) ? A : ((gtype == 1) ? U : G);
    size_t obase = ((size_t)b * C + oc) * HW + h * W + w;
#pragma unroll
    for (int j = 0; j < 8; ++j) {
        float r = 1.f / (1.f + __expf(-acc[j]));
        if (gtype == 1) r *= ip[(size_t)(oc + j) * HW];   // u = sigmoid(beta)*z
        dst[obase + (size_t)j * HW] = r;
    }
}

// ---------------- 1x1 conv, 8 outputs/thread ----------------
// MODE 0: plain (+bias). MODE 2: +bias + x residual.
template <int MODE>
__global__ void conv1x1_kernel(const float* __restrict__ in, const float* __restrict__ wgt,
                               const float* __restrict__ bias, const float* __restrict__ xres,
                               float* __restrict__ out) {
    int w = threadIdx.x;
    int o0 = blockIdx.x * 8;
    int bh = blockIdx.y;
    int b = bh / H, h = bh % H;
    float acc[8];
#pragma unroll
    for (int j = 0; j < 8; ++j) acc[j] = bias[o0 + j];
    const float* ip = in + (size_t)b * CHW + h * W + w;
#pragma unroll 4
    for (int c = 0; c < C; ++c) {
        float v = ip[(size_t)c * HW];
#pragma unroll
        for (int j = 0; j < 8; ++j)
            acc[j] += wgt[(o0 + j) * C + c] * v;
    }
    size_t obase = ((size_t)b * C + o0) * HW + h * W + w;
#pragma unroll
    for (int j = 0; j < 8; ++j) {
        float r = acc[j];
        if (MODE == 2) r += xres[obase + (size_t)j * HW];
        out[obase + (size_t)j * HW] = r;
    }
}

// ---------------- 3x3 depthwise conv, pad 1, no bias ----------------
// grid: (nb*C, HW/256), block 256
__global__ void dw3x3_kernel(const float* __restrict__ z, const float* __restrict__ wgt,
                             float* __restrict__ out) {
    int bc = blockIdx.x;
    int c = bc % C;
    int hw = blockIdx.y * 256 + threadIdx.x;
    int h = hw >> 7, w = hw & 127;
    const float* zp = z + (size_t)bc * HW;
    float k[9];
#pragma unroll
    for (int i = 0; i < 9; ++i) k[i] = wgt[c * 9 + i];
    float acc = 0.f;
#pragma unroll
    for (int ky = 0; ky < 3; ++ky) {
        int hh = h + ky - 1;
        if (hh < 0 || hh >= H) continue;
#pragma unroll
        for (int kx = 0; kx < 3; ++kx) {
            int ww = w + kx - 1;
            if (ww < 0 || ww >= W) continue;
            acc += k[ky * 3 + kx] * zp[hh * W + ww];
        }
    }
    out[(size_t)bc * HW + hw] = acc;
}

// ---------------- bidirectional scan along W (one wave per row) ----------------
// S += 0.5*g*(s_f + s_b); A/U/G are [nb][C][H][W]
__global__ void wscan_kernel(const float* __restrict__ A_, const float* __restrict__ U_,
                             const float* __restrict__ G_, float* __restrict__ S) {
    int wid = threadIdx.x >> 6;
    int lane = threadIdx.x & 63;
    int r = blockIdx.x * 4 + wid;            // row in [0, nb*C*H)
    size_t base = (size_t)r * W;

    float2 av = *(const float2*)(A_ + base + 2 * lane);
    float2 uv = *(const float2*)(U_ + base + 2 * lane);
    float2 gv = *(const float2*)(G_ + base + 2 * lane);
    float a0 = av.x, a1 = av.y;
    float u0 = uv.x, u1 = uv.y;

    // forward inclusive scan
    float A = a0 * a1;
    float U = a1 * u0 + u1;
#pragma unroll
    for (int d = 1; d < 64; d <<= 1) {
        float Ao = __shfl_up(A, (unsigned)d, 64);
        float Uo = __shfl_up(U, (unsigned)d, 64);
        if (lane >= d) { U = A * Uo + U; A = A * Ao; }
    }
    float sp = __shfl_up(U, 1u, 64);
    if (lane == 0) sp = 0.f;
    float s0 = a0 * sp + u0;
    float s1 = a1 * s0 + u1;

    // backward inclusive scan
    A = a0 * a1;
    U = a0 * u1 + u0;
#pragma unroll
    for (int d = 1; d < 64; d <<= 1) {
        float Ao = __shfl_down(A, (unsigned)d, 64);
        float Uo = __shfl_down(U, (unsigned)d, 64);
        if (lane + d < 64) { U = A * Uo + U; A = A * Ao; }
    }
    float tn = __shfl_down(U, 1u, 64);
    if (lane == 63) tn = 0.f;
    float t1 = a1 * tn + u1;
    float t0 = a0 * t1 + u0;

    float2* sptr = (float2*)(S + base + 2 * lane);
    float2 cur = *sptr;
    cur.x += 0.5f * gv.x * (s0 + t0);
    cur.y += 0.5f * gv.y * (s1 + t1);
    *sptr = cur;
}

// ---------------- bidirectional scan along H + fused silu on final write ----------
// grid: nb*C blocks of 128 (thread per w column)
__global__ void hscan_silu_kernel(const float* __restrict__ A_, const float* __restrict__ U_,
                                  const float* __restrict__ G_, float* __restrict__ S) {
    int bc = blockIdx.x;
    int w = threadIdx.x;
    size_t base = (size_t)bc * HW + w;

    float s = 0.f;
    for (int h = 0; h < H; ++h) {
        size_t off = base + (size_t)h * W;
        s = A_[off] * s + U_[off];
        S[off] += 0.5f * G_[off] * s;
    }
    s = 0.f;
    for (int h = H - 1; h >= 0; --h) {
        size_t off = base + (size_t)h * W;
        s = A_[off] * s + U_[off];
        float v = S[off] + 0.5f * G_[off] * s;
        S[off] = v / (1.f + __expf(-v));     // silu fused (final write)
    }
}

extern "C" void kernel_launch(void* const* d_in, const int* in_sizes, int n_in,
                              void* d_out, int out_size, void* d_ws, size_t ws_size,
                              hipStream_t stream) {
    const float* x     = (const float*)d_in[0];
    const float* ln_w  = (const float*)d_in[1];
    const float* ln_b  = (const float*)d_in[2];
    const float* dw_w  = (const float*)d_in[3];
    const float* loc_w = (const float*)d_in[4];
    const float* loc_b = (const float*)d_in[5];
    const float* par_w = (const float*)d_in[6];
    const float* par_b = (const float*)d_in[7];
    const float* out_w = (const float*)d_in[8];
    const float* out_b = (const float*)d_in[9];
    float* out = (float*)d_out;
    float* ws  = (float*)d_ws;

    // choose the largest batch group whose ws footprint (4 * nb * CHW floats) fits
    int nb = 8;
    while (nb > 1 && (size_t)4 * nb * CHW * sizeof(float) > ws_size) nb >>= 1;

    for (int b0 = 0; b0 < B; b0 += nb) {
        const float* xg = x + (size_t)b0 * CHW;
        float* og = out + (size_t)b0 * CHW;
        float* Z = ws;                          // nb*CHW  (reused as S after dwconv)
        float* A = ws + (size_t)nb * CHW;       // nb*CHW
        float* U = ws + (size_t)2 * nb * CHW;   // nb*CHW
        float* G = ws + (size_t)3 * nb * CHW;   // nb*CHW
        float* S = Z;

        // 1. LayerNorm -> Z
        ln_kernel<<<nb * HW / 256, 256, 0, stream>>>(xg, ln_w, ln_b, Z);
        // 2. gate conv (+sigmoid, u=beta*z fused) -> A, U, G
        gates_conv_kernel<<<dim3(3 * C / 8, nb * H), 128, 0, stream>>>(Z, par_w, par_b, A, U, G);
        // 3. depthwise 3x3 -> d_out region (scratch)
        dw3x3_kernel<<<dim3(nb * C, HW / 256), 256, 0, stream>>>(Z, dw_w, og);
        // 4. local 1x1 conv -> S (overwrites Z, which is now dead)
        conv1x1_kernel<0><<<dim3(C / 8, nb * H), 128, 0, stream>>>(og, loc_w, loc_b, nullptr, S);
        // 5. W-scan accumulate
        wscan_kernel<<<nb * C * H / 4, 256, 0, stream>>>(A, U, G, S);
        // 6. H-scan accumulate + silu on final write
        hscan_silu_kernel<<<nb * C, 128, 0, stream>>>(A, U, G, S);
        // 7. out conv + bias + residual -> d_out
        conv1x1_kernel<2><<<dim3(C / 8, nb * H), 128, 0, stream>>>(S, out_w, out_b, xg, og);
    }
}

// Round 4
// 784.911 us; speedup vs baseline: 1.8069x; 1.8069x over previous
//
#include <hip/hip_runtime.h>
#include <cstdint>
#include <cstddef>

#define B 8
#define C 192
#define H 128
#define W 128
#define HW (H * W)
#define CHW ((size_t)C * HW)
#define K C                    // GEMM K dim = 192

typedef __attribute__((ext_vector_type(8))) short short8v;
typedef __attribute__((ext_vector_type(4))) float f32x4;

__device__ __forceinline__ float bf2f(unsigned short s) {
    union { float f; unsigned u; } cv; cv.u = ((unsigned)s) << 16; return cv.f;
}
__device__ __forceinline__ unsigned short f2bf(float f) {
    union { float f; unsigned u; } cv; cv.f = f;
    unsigned r = (cv.u + 0x7fffu + ((cv.u >> 16) & 1u)) >> 16;
    return (unsigned short)r;
}

// ---------------- weight prepack fp32 -> bf16 (par | loc | out) ----------------
__global__ void prepack_kernel(const float* __restrict__ pw, const float* __restrict__ lw,
                               const float* __restrict__ ow, unsigned short* __restrict__ wb) {
    int i = blockIdx.x * 256 + threadIdx.x;
    const int NPW = 3 * C * K, NL = C * K;
    if (i < NPW) wb[i] = f2bf(pw[i]);
    else if (i < NPW + NL) wb[i] = f2bf(lw[i - NPW]);
    else if (i < NPW + 2 * NL) wb[i] = f2bf(ow[i - NPW - NL]);
}

// ---------------- LayerNorm over C -> z_t [p][K] bf16 (group-local) ----------------
__global__ void ln_kernel(const float* __restrict__ x, const float* __restrict__ lw,
                          const float* __restrict__ lb, unsigned short* __restrict__ zt) {
    int p = blockIdx.x * 256 + threadIdx.x;   // [0, nb*HW)
    int b = p >> 14, hw = p & 16383;
    const float* xp = x + (size_t)b * CHW + hw;
    float sum = 0.f, sq = 0.f;
    for (int c = 0; c < C; ++c) {
        float v = xp[(size_t)c * HW];
        sum += v; sq += v * v;
    }
    float mean = sum * (1.0f / C);
    float var = fmaxf(sq * (1.0f / C) - mean * mean, 0.f);
    float rs = rsqrtf(var + 1e-6f);
    unsigned short* zp = zt + (size_t)p * K;
#pragma unroll 4
    for (int c8 = 0; c8 < K / 8; ++c8) {
        short8v v;
#pragma unroll
        for (int j = 0; j < 8; ++j) {
            int c = c8 * 8 + j;
            float r = (xp[(size_t)c * HW] - mean) * rs * lw[c] + lb[c];
            v[j] = (short)f2bf(r);
        }
        *(short8v*)(zp + c8 * 8) = v;
    }
}

// ---------------- MFMA 1x1 conv: D[o][p] = W[o][:] . Zt[p][:] ----------------
// OTPB = output 16-tiles per block (blockIdx.y offsets by OTPB).
// MODE 0: gates (sigmoid; blockIdx.y: 0->A, 1->U(*=z), 2->G; bf16 NCHW out)
// MODE 1: +bias -> Pf (NCHW fp32)
// MODE 2: +bias +x residual -> Pf (NCHW fp32)
template <int OTPB, int MODE>
__global__ void conv_mfma_kernel(const unsigned short* __restrict__ zt,
                                 const unsigned short* __restrict__ wb,
                                 const float* __restrict__ bias, const float* __restrict__ xres,
                                 float* __restrict__ Pf, unsigned short* __restrict__ PA,
                                 unsigned short* __restrict__ PU, unsigned short* __restrict__ PG) {
    int lane = threadIdx.x & 63;
    int wv = threadIdx.x >> 6;
    int p0 = blockIdx.x * 256 + wv * 64;
    int lr = lane & 15, lh = lane >> 4;

    short8v bfr[4][6];
#pragma unroll
    for (int s = 0; s < 4; ++s)
#pragma unroll
        for (int t = 0; t < 6; ++t)
            bfr[s][t] = *(const short8v*)(zt + (size_t)(p0 + s * 16 + lr) * K + t * 32 + lh * 8);

    for (int i = 0; i < OTPB; ++i) {
        int ot = blockIdx.y * OTPB + i;
        f32x4 acc[4];
#pragma unroll
        for (int s = 0; s < 4; ++s) acc[s] = (f32x4){0.f, 0.f, 0.f, 0.f};
#pragma unroll
        for (int t = 0; t < 6; ++t) {
            short8v af = *(const short8v*)(wb + (size_t)(ot * 16 + lr) * K + t * 32 + lh * 8);
#pragma unroll
            for (int s = 0; s < 4; ++s)
                acc[s] = __builtin_amdgcn_mfma_f32_16x16x32_bf16(af, bfr[s][t], acc[s], 0, 0, 0);
        }
#pragma unroll
        for (int s = 0; s < 4; ++s) {
            int p = p0 + s * 16 + lr;
            int bidx = p >> 14, hw = p & 16383;
#pragma unroll
            for (int j = 0; j < 4; ++j) {
                int o = ot * 16 + lh * 4 + j;          // global output channel
                float v = acc[s][j] + bias[o];
                if (MODE == 0) {
                    v = 1.f / (1.f + __expf(-v));
                    int gy = blockIdx.y;
                    int oc = o - gy * C;
                    if (gy == 1) v *= bf2f(zt[(size_t)p * K + oc]);
                    unsigned short* dst = (gy == 0) ? PA : ((gy == 1) ? PU : PG);
                    dst[(size_t)bidx * CHW + (size_t)oc * HW + hw] = f2bf(v);
                } else if (MODE == 1) {
                    Pf[(size_t)bidx * CHW + (size_t)o * HW + hw] = v;
                } else {
                    size_t a = (size_t)bidx * CHW + (size_t)o * HW + hw;
                    Pf[a] = v + xres[a];
                }
            }
        }
    }
}

// ---------------- 3x3 depthwise conv on z_t -> d_t [p][K] bf16 ----------------
__global__ void dw3x3_kernel(const unsigned short* __restrict__ zt, const float* __restrict__ wgt,
                             unsigned short* __restrict__ dt) {
    int p = blockIdx.x * 256 + threadIdx.x;
    int hw = p & 16383, h = hw >> 7, w = hw & 127;
#pragma unroll 2
    for (int c8 = 0; c8 < K / 8; ++c8) {
        float kw[8][9];
#pragma unroll
        for (int j = 0; j < 8; ++j)
#pragma unroll
            for (int t = 0; t < 9; ++t) kw[j][t] = wgt[(c8 * 8 + j) * 9 + t];
        float acc[8];
#pragma unroll
        for (int j = 0; j < 8; ++j) acc[j] = 0.f;
#pragma unroll
        for (int dy = -1; dy <= 1; ++dy) {
            if (h + dy < 0 || h + dy >= H) continue;
#pragma unroll
            for (int dx = -1; dx <= 1; ++dx) {
                if (w + dx < 0 || w + dx >= W) continue;
                short8v zv = *(const short8v*)(zt + (size_t)(p + dy * W + dx) * K + c8 * 8);
                int t = (dy + 1) * 3 + (dx + 1);
#pragma unroll
                for (int j = 0; j < 8; ++j) acc[j] += kw[j][t] * bf2f((unsigned short)zv[j]);
            }
        }
        short8v ov;
#pragma unroll
        for (int j = 0; j < 8; ++j) ov[j] = (short)f2bf(acc[j]);
        *(short8v*)(dt + (size_t)p * K + c8 * 8) = ov;
    }
}

// ---------------- bidirectional scan along W (one wave per row) ----------------
__global__ void wscan_kernel(const unsigned short* __restrict__ A_, const unsigned short* __restrict__ U_,
                             const unsigned short* __restrict__ G_, float* __restrict__ S) {
    int wid = threadIdx.x >> 6;
    int lane = threadIdx.x & 63;
    int r = blockIdx.x * 4 + wid;            // row in [0, nb*C*H)
    size_t base = (size_t)r * W;

    ushort2 av = *(const ushort2*)(A_ + base + 2 * lane);
    ushort2 uv = *(const ushort2*)(U_ + base + 2 * lane);
    ushort2 gv = *(const ushort2*)(G_ + base + 2 * lane);
    float a0 = bf2f(av.x), a1 = bf2f(av.y);
    float u0 = bf2f(uv.x), u1 = bf2f(uv.y);

    float A = a0 * a1;
    float U = a1 * u0 + u1;
#pragma unroll
    for (int d = 1; d < 64; d <<= 1) {
        float Ao = __shfl_up(A, (unsigned)d, 64);
        float Uo = __shfl_up(U, (unsigned)d, 64);
        if (lane >= d) { U = A * Uo + U; A = A * Ao; }
    }
    float sp = __shfl_up(U, 1u, 64);
    if (lane == 0) sp = 0.f;
    float s0 = a0 * sp + u0;
    float s1 = a1 * s0 + u1;

    A = a0 * a1;
    U = a0 * u1 + u0;
#pragma unroll
    for (int d = 1; d < 64; d <<= 1) {
        float Ao = __shfl_down(A, (unsigned)d, 64);
        float Uo = __shfl_down(U, (unsigned)d, 64);
        if (lane + d < 64) { U = A * Uo + U; A = A * Ao; }
    }
    float tn = __shfl_down(U, 1u, 64);
    if (lane == 63) tn = 0.f;
    float t1 = a1 * tn + u1;
    float t0 = a0 * t1 + u0;

    float2* sptr = (float2*)(S + base + 2 * lane);
    float2 cur = *sptr;
    cur.x += 0.5f * bf2f(gv.x) * (s0 + t0);
    cur.y += 0.5f * bf2f(gv.y) * (s1 + t1);
    *sptr = cur;
}

// ---------------- bidirectional scan along H ----------------
__global__ void hscan_kernel(const unsigned short* __restrict__ A_, const unsigned short* __restrict__ U_,
                             const unsigned short* __restrict__ G_, float* __restrict__ S) {
    int bc = blockIdx.x;
    int w = threadIdx.x;
    size_t base = (size_t)bc * HW + w;
    float s = 0.f;
    for (int h = 0; h < H; ++h) {
        size_t off = base + (size_t)h * W;
        s = bf2f(A_[off]) * s + bf2f(U_[off]);
        S[off] += 0.5f * bf2f(G_[off]) * s;
    }
    s = 0.f;
    for (int h = H - 1; h >= 0; --h) {
        size_t off = base + (size_t)h * W;
        s = bf2f(A_[off]) * s + bf2f(U_[off]);
        S[off] += 0.5f * bf2f(G_[off]) * s;
    }
}

// ---------------- transpose + silu: S (NCHW f32) -> S_t [p][K] bf16 ----------------
__global__ void tsilu_kernel(const float* __restrict__ S, unsigned short* __restrict__ st) {
    int p = blockIdx.x * 256 + threadIdx.x;
    int b = p >> 14, hw = p & 16383;
    const float* sp = S + (size_t)b * CHW + hw;
    unsigned short* op = st + (size_t)p * K;
#pragma unroll 4
    for (int c8 = 0; c8 < K / 8; ++c8) {
        short8v v;
#pragma unroll
        for (int j = 0; j < 8; ++j) {
            float x = sp[(size_t)(c8 * 8 + j) * HW];
            x = x / (1.f + __expf(-x));
            v[j] = (short)f2bf(x);
        }
        *(short8v*)(op + c8 * 8) = v;
    }
}

extern "C" void kernel_launch(void* const* d_in, const int* in_sizes, int n_in,
                              void* d_out, int out_size, void* d_ws, size_t ws_size,
                              hipStream_t stream) {
    const float* x     = (const float*)d_in[0];
    const float* ln_w  = (const float*)d_in[1];
    const float* ln_b  = (const float*)d_in[2];
    const float* dw_w  = (const float*)d_in[3];
    const float* loc_w = (const float*)d_in[4];
    const float* loc_b = (const float*)d_in[5];
    const float* par_w = (const float*)d_in[6];
    const float* par_b = (const float*)d_in[7];
    const float* out_w = (const float*)d_in[8];
    const float* out_b = (const float*)d_in[9];
    float* out = (float*)d_out;
    unsigned short* wsu = (unsigned short*)d_ws;

    // ws (bf16 units): WB(184320) | A | U | G | ZT(->ST) | DT, each nb*CHW
    const int WBN = 3 * C * K + 2 * C * K;     // 184320
    int nb = 8;
    while (nb > 1) {
        size_t need = (size_t)WBN * 2 + (size_t)5 * nb * CHW * 2;
        if (need <= ws_size) break;
        nb >>= 1;
    }

    prepack_kernel<<<(WBN + 255) / 256, 256, 0, stream>>>(par_w, loc_w, out_w, wsu);

    for (int b0 = 0; b0 < B; b0 += nb) {
        size_t ge = (size_t)nb * CHW;
        unsigned short* WB = wsu;
        unsigned short* Ab = wsu + WBN;
        unsigned short* Ub = Ab + ge;
        unsigned short* Gb = Ub + ge;
        unsigned short* ZT = Gb + ge;          // reused as ST after dwconv
        unsigned short* DT = ZT + ge;
        const float* xg = x + (size_t)b0 * CHW;
        float* Sg = out + (size_t)b0 * CHW;    // d_out doubles as fp32 S accumulator
        int npg = nb * HW;

        ln_kernel<<<npg / 256, 256, 0, stream>>>(xg, ln_w, ln_b, ZT);
        conv_mfma_kernel<12, 0><<<dim3(npg / 256, 3), 256, 0, stream>>>(
            ZT, WB, par_b, nullptr, nullptr, Ab, Ub, Gb);
        dw3x3_kernel<<<npg / 256, 256, 0, stream>>>(ZT, dw_w, DT);
        conv_mfma_kernel<12, 1><<<dim3(npg / 256, 1), 256, 0, stream>>>(
            DT, WB + 3 * C * K, loc_b, nullptr, Sg, nullptr, nullptr, nullptr);
        wscan_kernel<<<nb * C * H / 4, 256, 0, stream>>>(Ab, Ub, Gb, Sg);
        hscan_kernel<<<nb * C, 128, 0, stream>>>(Ab, Ub, Gb, Sg);
        tsilu_kernel<<<npg / 256, 256, 0, stream>>>(Sg, ZT);
        conv_mfma_kernel<12, 2><<<dim3(npg / 256, 1), 256, 0, stream>>>(
            ZT, WB + 3 * C * K + C * K, out_b, xg, out + (size_t)b0 * CHW,
            nullptr, nullptr, nullptr);
    }
}